// Round 11
// baseline (328.745 us; speedup 1.0000x reference)
//
#include <hip/hip_runtime.h>
#include <hip/hip_bf16.h>

#define S_LEN 2048
#define D_MODEL 768
#define NH 12
#define DK 64
#define F_DIM 3072
#define BATCH 2
#define M_ROWS (BATCH * S_LEN)   // 4096

typedef __bf16 bf16x8 __attribute__((ext_vector_type(8)));
typedef float floatx4 __attribute__((ext_vector_type(4)));
typedef unsigned short u16;
typedef unsigned long long u64;

__device__ inline float bf2f(u16 u) {
    union { unsigned int i; float f; } x; x.i = ((unsigned int)u) << 16; return x.f;
}
__device__ inline u16 f2bf(float f) {
    union { float f; unsigned int i; } x; x.f = f;
    unsigned int r = x.i + 0x7fffu + ((x.i >> 16) & 1u);
    return (u16)(r >> 16);
}
__device__ __forceinline__ bf16x8 as_bf16x8(uint4 v) {
    union { uint4 u; bf16x8 b; } c; c.u = v; return c.b;
}

// async global->LDS, 16B per lane; LDS dest is wave-uniform base + lane*16
__device__ __forceinline__ void ldsload16(const u16* g, u16* l) {
    __builtin_amdgcn_global_load_lds(
        (const __attribute__((address_space(1))) unsigned int*)g,
        (__attribute__((address_space(3))) unsigned int*)l, 16, 0, 0);
}

// ---------------- merged preprocessing: cvt + mask_bits + rmsnorm1 ----------
// v2: grid-strided to 3200 blocks total (was 17408 tiny blocks — launch/
// scheduling overhead); rms part is wave-per-row (no cross-wave barrier).
__device__ __forceinline__ void cvt_body(
        int i,
        const float4* wq, const float4* wk, const float4* wv, const float4* wo,
        const float4* w1, const float4* w2, const float4* w3,
        ushort4* wqkvf, ushort4* wob, ushort4* w13f, ushort4* w2b) {
    const int WS4 = (D_MODEL * D_MODEL) / 4;   // 147456
    const int WB4 = (F_DIM * D_MODEL) / 4;     // 589824
    const int RW4 = D_MODEL / 4;               // 192 float4 per row
    const float4* src; ushort4* dst; int off, doff;
    if (i < 4 * WS4) {
        int s = i / WS4; off = i - s * WS4;
        src = (s == 0) ? wq : (s == 1) ? wk : (s == 2) ? wv : wo;
        if (s == 3) { dst = wob; doff = off; }
        else {
            dst = wqkvf;
            int row = off / RW4, c4 = off - row * RW4;
            int k = c4 * 4;
            int rg = s * D_MODEL + row;          // global row 0..2303
            int n_tile = rg >> 4, nl = rg & 15;
            int k_tile = k >> 5, qd = (k >> 3) & 3, jj = k & 7;
            int ln = qd * 16 + nl;
            int f = n_tile * 24 + k_tile;
            doff = (f * 512 + ln * 8 + jj) >> 2;
        }
    } else {
        int j = i - 4 * WS4; int s = j / WB4; off = j - s * WB4;
        if (s == 1) { src = w2; dst = w2b; doff = off; }
        else {
            src = (s == 0) ? w1 : w3;
            dst = w13f;
            int which = (s == 0) ? 0 : 1;
            int row = off / RW4, c4 = off - row * RW4;
            int k = c4 * 4;
            int n_tile = row >> 4, nl = row & 15;
            int k_tile = k >> 5, qd = (k >> 3) & 3, jj = k & 7;
            int ln = qd * 16 + nl;
            int f = (n_tile * 24 + k_tile) * 2 + which;
            doff = (f * 512 + ln * 8 + jj) >> 2;
        }
    }
    float4 v = src[off];
    ushort4 o;
    o.x = f2bf(v.x); o.y = f2bf(v.y); o.z = f2bf(v.z); o.w = f2bf(v.w);
    dst[doff] = o;
}

// wave-per-row RMSNorm body: lane covers 12 elems (row = 768 = 64 lanes x 12)
__device__ __forceinline__ void rms_row_wave(int row, const float* x,
                                             const float* g, u16* out) {
    int lane = threadIdx.x & 63;
    const float* xr = x + (size_t)row * D_MODEL;
    u16* orow = out + (size_t)row * D_MODEL;
    float v[12];
    float ss = 0.f;
    #pragma unroll
    for (int i = 0; i < 12; ++i) {
        v[i] = xr[lane + 64 * i];
        ss += v[i] * v[i];
    }
    #pragma unroll
    for (int off = 1; off < 64; off <<= 1) ss += __shfl_xor(ss, off);
    float scale = rsqrtf(ss * (1.0f / (float)D_MODEL) + 1e-5f);
    #pragma unroll
    for (int i = 0; i < 12; ++i)
        orow[lane + 64 * i] = f2bf(g[lane + 64 * i] * v[i] * scale);
}

// grid = 1152 (cvt x8) + 1024 (mask x32) + 1024 (rms x4 rows) = 3200 blocks
__global__ __launch_bounds__(256)
void prep(const float4* wq, const float4* wk, const float4* wv, const float4* wo,
          const float4* w1, const float4* w2, const float4* w3,
          ushort4* wqkvf, ushort4* wob, ushort4* w13f, ushort4* w2b,
          const int* m, u64* bits,
          const float* x, const float* g, u16* xn) {
    int bx = blockIdx.x;
    if (bx < 1152) {
        #pragma unroll
        for (int it = 0; it < 8; ++it)
            cvt_body(bx * 2048 + it * 256 + threadIdx.x,
                     wq, wk, wv, wo, w1, w2, w3, wqkvf, wob, w13f, w2b);
    } else if (bx < 2176) {
        size_t base = (size_t)(bx - 1152) * 8192 + threadIdx.x;
        #pragma unroll
        for (int it = 0; it < 32; ++it) {
            size_t gid = base + (size_t)it * 256;
            u64 b = __ballot(m[gid] != 0);
            if ((threadIdx.x & 63) == 0) bits[gid >> 6] = b;
        }
    } else {
        int row = (bx - 2176) * 4 + (threadIdx.x >> 6);
        rms_row_wave(row, x, g, xn);
    }
}

// ---------------- RMSNorm standalone (for the h -> hn call) -----------------
// v2: wave-per-row, 4 rows/block, no __syncthreads. grid = M_ROWS/4.
__global__ __launch_bounds__(256)
void rmsnorm_k(const float* __restrict__ x, const float* __restrict__ g, u16* __restrict__ out) {
    int row = blockIdx.x * 4 + (threadIdx.x >> 6);
    rms_row_wave(row, x, g, out);
}

// ---------------- FFN1: direct-global B-frags, A LDS-staged -----------------
// Block = 64m x 128out (4 waves, each 64m x 32out-pair). B-frags stream from
// global (L2) in fragment layout; XCD-swizzled grid keeps each XCD's weight
// slice L2-resident. C(bf16) = silu(A@w1^T) * (A@w3^T).
// v3: BK=64, 12 phases; B-frag loads issued before the barrier (latency
// overlaps the drain).
__global__ __launch_bounds__(256, 3)
void gemm_f1(const u16* __restrict__ A, const u16* __restrict__ W13f,
             u16* __restrict__ Cout) {
    const int K = D_MODEL, N = F_DIM;
    __shared__ u16 As[2][64][64];

    int t = threadIdx.x;
    int w = t >> 6, lane = t & 63;
    int lrow = lane & 15, quad = lane >> 4;

    int lid = blockIdx.y * 24 + blockIdx.x;
    int xcd = lid & 7, s = lid >> 3;          // 192 blocks per xcd
    int nb = xcd * 3 + (s % 3);               // 0..23
    int mb = s / 3;                           // 0..63
    int mBase = mb * 64;
    int ntile0 = nb * 8 + w * 2;              // wave's first n-tile

    int srow8 = lane >> 3;
    int sc64 = ((lane & 7) ^ srow8) * 8;
    const u16* Ag = A + (size_t)(mBase + w * 16 + srow8) * K + sc64;
    const uint4* Bf = (const uint4*)W13f;

    auto stageA = [&](int k0, int b) {
        ldsload16(Ag + k0,                 &As[b][w * 16][0]);
        ldsload16(Ag + (size_t)8 * K + k0, &As[b][w * 16 + 8][0]);
    };

    floatx4 zero = {0.f, 0.f, 0.f, 0.f};
    floatx4 acc[4][2], acc2[4][2];
    #pragma unroll
    for (int r = 0; r < 4; ++r)
        #pragma unroll
        for (int c = 0; c < 2; ++c) { acc[r][c] = zero; acc2[r][c] = zero; }

    stageA(0, 0);
    int cur = 0;
    for (int kt2 = 0; kt2 < 12; ++kt2) {
        uint4 b1v[2][2], b3v[2][2];
        #pragma unroll
        for (int hh = 0; hh < 2; ++hh) {
            int kt = kt2 * 2 + hh;
            #pragma unroll
            for (int c = 0; c < 2; ++c) {
                int f = ((ntile0 + c) * 24 + kt) * 2;
                b1v[hh][c] = Bf[(size_t)f * 64 + lane];
                b3v[hh][c] = Bf[(size_t)(f + 1) * 64 + lane];
            }
        }
        __syncthreads();                       // stageA(kt2) landed
        if (kt2 + 1 < 12) stageA((kt2 + 1) * 64, cur ^ 1);

        #pragma unroll
        for (int hh = 0; hh < 2; ++hh) {
            int rc = ((hh * 4 + quad) ^ (lrow & 7)) * 8;   // swizzled read col
            bf16x8 af[4];
            #pragma unroll
            for (int r = 0; r < 4; ++r) af[r] = *(const bf16x8*)&As[cur][r * 16 + lrow][rc];
            #pragma unroll
            for (int c = 0; c < 2; ++c) {
                bf16x8 b1f = as_bf16x8(b1v[hh][c]);
                bf16x8 b3f = as_bf16x8(b3v[hh][c]);
                #pragma unroll
                for (int r = 0; r < 4; ++r) {
                    acc[r][c]  = __builtin_amdgcn_mfma_f32_16x16x32_bf16(af[r], b1f, acc[r][c], 0, 0, 0);
                    acc2[r][c] = __builtin_amdgcn_mfma_f32_16x16x32_bf16(af[r], b3f, acc2[r][c], 0, 0, 0);
                }
            }
        }
        cur ^= 1;
    }

    #pragma unroll
    for (int r = 0; r < 4; ++r) {
        #pragma unroll
        for (int c = 0; c < 2; ++c) {
            #pragma unroll
            for (int j = 0; j < 4; ++j) {
                int grow = mBase + r * 16 + quad * 4 + j;
                int gcol = nb * 128 + w * 32 + c * 16 + lrow;
                float a = acc[r][c][j];
                Cout[(size_t)grow * N + gcol] = f2bf((a / (1.0f + __expf(-a))) * acc2[r][c][j]);
            }
        }
    }
}

// ---------------- 64x64-tile GEMM + residual (for N=768 GEMMs) --------------
// v4: BK=64 + xor-swizzle + per-XCD (mChunk x all-n) mapping.
__global__ __launch_bounds__(256, 3)
void gemm64(const u16* __restrict__ A, const u16* __restrict__ B1,
            const float* __restrict__ R, float* __restrict__ Cout, int N, int K) {
    __shared__ u16 As[2][64][64];
    __shared__ u16 Bs[2][64][64];

    int t = threadIdx.x;
    int w = t >> 6, lane = t & 63;

    int L = blockIdx.y * gridDim.x + blockIdx.x;
    int xcd = L & 7;
    int i = L >> 3;                         // 0..per-1
    int nT = gridDim.x;                     // n-tiles (12)
    int mPer = gridDim.y >> 3;              // m-tiles per XCD (8)
    int nIdx = i % nT;
    int mIdx = xcd * mPer + i / nT;
    int mBase = mIdx * 64, nBase = nIdx * 64;

    int lrow = lane & 15, quad = lane >> 4;
    int wm = (w >> 1) * 32, wn = (w & 1) * 32;

    int srow8 = lane >> 3;                          // 0..7
    int sc64 = ((lane & 7) ^ srow8) * 8;            // swizzled source col (elems)
    const u16* Ag = A  + (size_t)(mBase + w * 16 + srow8) * K + sc64;
    const u16* Bg = B1 + (size_t)(nBase + w * 16 + srow8) * K + sc64;

    auto stage = [&](int k0, int b) {
        ldsload16(Ag + k0,                 &As[b][w * 16][0]);
        ldsload16(Ag + (size_t)8 * K + k0, &As[b][w * 16 + 8][0]);
        ldsload16(Bg + k0,                 &Bs[b][w * 16][0]);
        ldsload16(Bg + (size_t)8 * K + k0, &Bs[b][w * 16 + 8][0]);
    };

    floatx4 zero = {0.f, 0.f, 0.f, 0.f};
    floatx4 acc[2][2];
    #pragma unroll
    for (int r = 0; r < 2; ++r)
        #pragma unroll
        for (int c = 0; c < 2; ++c) acc[r][c] = zero;

    stage(0, 0);
    int cur = 0;
    for (int k0 = 0; k0 < K; k0 += 64) {
        __syncthreads();
        if (k0 + 64 < K) stage(k0 + 64, cur ^ 1);

        #pragma unroll
        for (int half = 0; half < 2; ++half) {
            int rc = ((half * 4 + quad) ^ (lrow & 7)) * 8;   // swizzled read col
            bf16x8 af[2], bf[2];
            #pragma unroll
            for (int r = 0; r < 2; ++r) af[r] = *(const bf16x8*)&As[cur][wm + r * 16 + lrow][rc];
            #pragma unroll
            for (int c = 0; c < 2; ++c) bf[c] = *(const bf16x8*)&Bs[cur][wn + c * 16 + lrow][rc];
            #pragma unroll
            for (int r = 0; r < 2; ++r)
                #pragma unroll
                for (int c = 0; c < 2; ++c)
                    acc[r][c] = __builtin_amdgcn_mfma_f32_16x16x32_bf16(af[r], bf[c], acc[r][c], 0, 0, 0);
        }
        cur ^= 1;
    }

    #pragma unroll
    for (int r = 0; r < 2; ++r) {
        #pragma unroll
        for (int c = 0; c < 2; ++c) {
            #pragma unroll
            for (int j = 0; j < 4; ++j) {
                int grow = mBase + wm + r * 16 + quad * 4 + j;
                int gcol = nBase + wn + c * 16 + lrow;
                size_t idx = (size_t)grow * N + gcol;
                Cout[idx] = acc[r][c][j] + R[idx];
            }
        }
    }
}

// ---------------- fused QKV GEMM: f1-structure port -------------------------
// v4: B-frags direct from global in fragment order (wqkvf, [2304x768]), no
// B LDS; A-only LDS, BK=64, 12 phases. Block = 64m x 128out. XCD swizzle.
// Q pre-scaled by 0.125*log2(e); V stored transposed.
__global__ __launch_bounds__(256, 4)
void gemm_qkv(const u16* __restrict__ A, const u16* __restrict__ Wf,
              u16* __restrict__ qb, u16* __restrict__ kb, u16* __restrict__ vt) {
    const int K = D_MODEL;
    __shared__ u16 As[2][64][64];

    int t = threadIdx.x;
    int w = t >> 6, lane = t & 63;
    int lrow = lane & 15, quad = lane >> 4;

    int L = blockIdx.y * 18 + blockIdx.x;
    int g = (L & 7) * 144 + (L >> 3);            // 1152 blocks, 144 per XCD
    int nb = g >> 6;                              // 0..17 (128-col block)
    int mBase = (g & 63) * 64;
    int ntile0 = nb * 8 + w * 2;                  // wave's first n-tile (0..143)

    int srow8 = lane >> 3;
    int sc64 = ((lane & 7) ^ srow8) * 8;
    const u16* Ag = A + (size_t)(mBase + w * 16 + srow8) * K + sc64;
    const uint4* Bf = (const uint4*)Wf;

    auto stageA = [&](int k0, int b) {
        ldsload16(Ag + k0,                 &As[b][w * 16][0]);
        ldsload16(Ag + (size_t)8 * K + k0, &As[b][w * 16 + 8][0]);
    };

    floatx4 zero = {0.f, 0.f, 0.f, 0.f};
    floatx4 acc[4][2];
    #pragma unroll
    for (int r = 0; r < 4; ++r)
        #pragma unroll
        for (int c = 0; c < 2; ++c) acc[r][c] = zero;

    stageA(0, 0);
    int cur = 0;
    for (int kt2 = 0; kt2 < 12; ++kt2) {
        uint4 bv[2][2];
        #pragma unroll
        for (int hh = 0; hh < 2; ++hh) {
            int kt = kt2 * 2 + hh;
            #pragma unroll
            for (int c = 0; c < 2; ++c) {
                int f = (ntile0 + c) * 24 + kt;
                bv[hh][c] = Bf[(size_t)f * 64 + lane];
            }
        }
        __syncthreads();                       // stageA(kt2) landed
        if (kt2 + 1 < 12) stageA((kt2 + 1) * 64, cur ^ 1);

        #pragma unroll
        for (int hh = 0; hh < 2; ++hh) {
            int rc = ((hh * 4 + quad) ^ (lrow & 7)) * 8;   // swizzled read col
            bf16x8 af[4];
            #pragma unroll
            for (int r = 0; r < 4; ++r) af[r] = *(const bf16x8*)&As[cur][r * 16 + lrow][rc];
            #pragma unroll
            for (int c = 0; c < 2; ++c) {
                bf16x8 bfr = as_bf16x8(bv[hh][c]);
                #pragma unroll
                for (int r = 0; r < 4; ++r)
                    acc[r][c] = __builtin_amdgcn_mfma_f32_16x16x32_bf16(af[r], bfr, acc[r][c], 0, 0, 0);
            }
        }
        cur ^= 1;
    }

    const float qscale = 0.18033688011112042f;   // 0.125 * log2(e)
    int which = nb / 6;                           // all 128 cols same matrix
    u16* dst = (which == 0) ? qb : kb;
    #pragma unroll
    for (int r = 0; r < 4; ++r) {
        #pragma unroll
        for (int c = 0; c < 2; ++c) {
            #pragma unroll
            for (int j = 0; j < 4; ++j) {
                int grow = mBase + r * 16 + quad * 4 + j;
                int gcol = nb * 128 + w * 32 + c * 16 + lrow;   // 0..2303
                int cm = gcol - which * D_MODEL;                // col in matrix
                float val = acc[r][c][j];
                if (which == 2) {
                    int bb = grow >> 11, s = grow & 2047;
                    int hh = cm >> 6, d = cm & 63;
                    vt[((((size_t)bb * NH + hh) * DK + d) << 11) + s] = f2bf(val);
                } else {
                    if (which == 0) val *= qscale;
                    dst[(size_t)grow * D_MODEL + cm] = f2bf(val);
                }
            }
        }
    }
}

// ---------------- MFMA flash attention (S^T formulation) --------------------
// v9: K/V xor-swizzled LDS, Q in regs, PT cg-xor swizzled (40960B LDS),
// XCD-grouped blocks (K/V L2-resident). Floored at ~60us (grid = 3 blocks/CU
// exactly; issue/latency-bound, no pipe saturated).
__global__ __launch_bounds__(256)
void attn_mfma(const u16* __restrict__ q, const u16* __restrict__ k,
               const u16* __restrict__ vt, const u64* __restrict__ mbits,
               u16* __restrict__ out) {
    __shared__ u16 Ks0[2][64][32], Ks1[2][64][32];
    __shared__ u16 Vs0[2][64][32], Vs1[2][64][32];
    __shared__ u16 PT[4][16][64];     // per-wave P^T, cg-xor swizzled

    int t = threadIdx.x;
    int lane = t & 63;
    int w = t >> 6;
    int lrow = lane & 15;
    int quad = lane >> 4;

    // XCD swizzle: 768 blocks, 96/XCD = 3 bh-groups x 32 q-tiles
    int L = blockIdx.y * gridDim.x + blockIdx.x;   // gridDim.x = 32
    int g = (L & 7) * 96 + (L >> 3);
    int st0 = (g & 31) * 64;
    int bh = g >> 5;
    int h = bh % NH;
    int b = bh / NH;

    const u16* kbase = k + (size_t)b * S_LEN * D_MODEL + h * DK;
    const u16* vbase = vt + (size_t)bh * DK * S_LEN;
    const u64* bw = mbits + ((size_t)b * S_LEN + st0 + w * 16 + lrow) * (S_LEN / 64);

    int srow = lane >> 2;          // staging row within 16-row chunk
    int scolS = ((lane & 3) ^ ((lane >> 3) & 3)) * 8;   // staging source col
    int rq = (quad ^ ((lrow >> 1) & 3)) * 8;            // swizzled read col
    // PT swizzle terms (per-thread constants)
    int ptw = lrow & 7;
    int rp0 = (quad ^ ptw) * 8;           // logical cg = quad
    int rp1 = ((4 + quad) ^ ptw) * 8;     // logical cg = 4+quad
    int pqo = (quad & 1) * 4;             // uint2 sub-offset within group
    int pch = quad >> 1;

    const u16* kg = kbase + (size_t)(w * 16 + srow) * D_MODEL + scolS;
    const u16* vg = vbase + (size_t)(w * 16 + srow) * S_LEN + scolS;

    auto stageKV = [&](int kt, int bsel) {
        ldsload16(kg + (size_t)kt * D_MODEL,      &Ks0[bsel][w * 16][0]);
        ldsload16(kg + (size_t)kt * D_MODEL + 32, &Ks1[bsel][w * 16][0]);
        ldsload16(vg + kt,      &Vs0[bsel][w * 16][0]);
        ldsload16(vg + kt + 32, &Vs1[bsel][w * 16][0]);
    };

    stageKV(0, 0);

    // ---- Q fragments direct from global into regs (once per block) ----
    bf16x8 bq0, bq1;
    {
        const u16* qrow = q + ((size_t)b * S_LEN + st0 + w * 16 + lrow) * D_MODEL + h * DK + quad * 8;
        bq0 = *(const bf16x8*)qrow;
        bq1 = *(const bf16x8*)(qrow + 32);
    }

    // ones vector (bf16 1.0 x8) for MFMA row-sums
    bf16x8 ones;
    {
        union { u16 u; __bf16 b; } o; o.u = 0x3F80;
        #pragma unroll
        for (int j = 0; j < 8; ++j) ones[j] = o.b;
    }

    floatx4 zero = {0.f, 0.f, 0.f, 0.f};
    floatx4 Ot[4] = {zero, zero, zero, zero};
    floatx4 Osum = zero;              // row-sums of P (per-lane rows quad*4+j)

    u64 mw = bw[0];                   // mask bits for tile 0 (prefetched)
    __syncthreads();                  // stageKV(0) landed

    int cur = 0;
    for (int kt = 0; kt < S_LEN; kt += 64) {
        // prefetch next K/V tile -> other LDS buffer, mask word -> reg
        if (kt + 64 < S_LEN) stageKV(kt + 64, cur ^ 1);
        u64 mw_next = (kt + 64 < S_LEN) ? bw[(kt >> 6) + 1] : 0ull;
        unsigned mlo = (unsigned)mw, mhi = (unsigned)(mw >> 32);

        // --- S^T = K Q^T : 64 keys x 16 q per wave ---
        floatx4 st[4];
        #pragma unroll
        for (int nt = 0; nt < 4; ++nt) {
            bf16x8 ak0 = *(const bf16x8*)&Ks0[cur][nt * 16 + lrow][rq];
            bf16x8 ak1 = *(const bf16x8*)&Ks1[cur][nt * 16 + lrow][rq];
            st[nt] = __builtin_amdgcn_mfma_f32_16x16x32_bf16(ak0, bq0, zero, 0, 0, 0);
            st[nt] = __builtin_amdgcn_mfma_f32_16x16x32_bf16(ak1, bq1, st[nt], 0, 0, 0);
        }

        // --- P^T = maskbit * exp2(S^T), truncated to bf16, packed writes ---
        #pragma unroll
        for (int nt = 0; nt < 4; ++nt) {
            unsigned half = (nt & 2) ? mhi : mlo;
            unsigned tmp = half >> ((nt & 1) * 16 + quad * 4);
            unsigned eu[4];
            #pragma unroll
            for (int j = 0; j < 4; ++j) {
                float e = __builtin_amdgcn_exp2f(st[nt][j]);
                unsigned msk = (unsigned)((int)(tmp << (31 - j)) >> 31);
                eu[j] = __float_as_uint(e) & msk;
            }
            uint2 p;
            p.x = (eu[0] >> 16) | (eu[1] & 0xffff0000u);
            p.y = (eu[2] >> 16) | (eu[3] & 0xffff0000u);
            // logical col = nt*16 + quad*4 -> cg = nt*2 + (quad>>1)
            int pc = ((nt * 2 + pch) ^ ptw) * 8 + pqo;
            *(uint2*)&PT[w][lrow][pc] = p;
        }

        // --- O += P V ; row-sums += P * ones (on the MFMA pipe) ---
        bf16x8 ap0 = *(const bf16x8*)&PT[w][lrow][rp0];
        bf16x8 ap1 = *(const bf16x8*)&PT[w][lrow][rp1];
        Osum = __builtin_amdgcn_mfma_f32_16x16x32_bf16(ap0, ones, Osum, 0, 0, 0);
        Osum = __builtin_amdgcn_mfma_f32_16x16x32_bf16(ap1, ones, Osum, 0, 0, 0);
        #pragma unroll
        for (int dt = 0; dt < 4; ++dt) {
            bf16x8 bv0 = *(const bf16x8*)&Vs0[cur][dt * 16 + lrow][rq];
            bf16x8 bv1 = *(const bf16x8*)&Vs1[cur][dt * 16 + lrow][rq];
            Ot[dt] = __builtin_amdgcn_mfma_f32_16x16x32_bf16(ap0, bv0, Ot[dt], 0, 0, 0);
            Ot[dt] = __builtin_amdgcn_mfma_f32_16x16x32_bf16(ap1, bv1, Ot[dt], 0, 0, 0);
        }

        // single barrier per tile: all waves done reading buf[cur] (so next
        // iter may overwrite) and stageKV(kt+64) landed (vmcnt drain).
        __syncthreads();
        cur ^= 1;
        mw = mw_next;
    }

    // --- Osum[j] is the row-sum for q-row quad*4+j (cols identical) ---
    float invj[4];
    #pragma unroll
    for (int j = 0; j < 4; ++j) invj[j] = 1.0f / Osum[j];

    u16* obase = out + ((size_t)b * S_LEN + st0 + w * 16) * D_MODEL + h * DK;
    #pragma unroll
    for (int dt = 0; dt < 4; ++dt)
        #pragma unroll
        for (int j = 0; j < 4; ++j)
            obase[(size_t)(quad * 4 + j) * D_MODEL + dt * 16 + lrow] = f2bf(Ot[dt][j] * invj[j]);
}

// ---------------- host launch ----------------
extern "C" void kernel_launch(void* const* d_in, const int* in_sizes, int n_in,
                              void* d_out, int out_size, void* d_ws, size_t ws_size,
                              hipStream_t stream) {
    const float* x      = (const float*)d_in[0];
    const int*   mask   = (const int*)d_in[1];
    const float* wq     = (const float*)d_in[2];
    const float* wk     = (const float*)d_in[3];
    const float* wv     = (const float*)d_in[4];
    const float* wo     = (const float*)d_in[5];
    const float* w1     = (const float*)d_in[6];
    const float* w2     = (const float*)d_in[7];
    const float* w3     = (const float*)d_in[8];
    const float* g_attn = (const float*)d_in[9];
    const float* g_ffn  = (const float*)d_in[10];
    float* out = (float*)d_out;

    const size_t WSMALL = (size_t)D_MODEL * D_MODEL;
    const size_t WBIG   = (size_t)F_DIM * D_MODEL;
    const size_t MD     = (size_t)M_ROWS * D_MODEL;

    char* ws = (char*)d_ws;
    u16* wqkvf = (u16*)ws;           ws += WSMALL * 3 * 2;  // frag-ordered wq|wk|wv
    u16* wob  = (u16*)ws;            ws += WSMALL * 2;
    u16* w13f = (u16*)ws;            ws += WBIG * 2 * 2;   // frag-ordered w1|w3
    u16* w2b  = (u16*)ws;            ws += WBIG * 2;
    u16* xn  = (u16*)ws;             ws += MD * 2;       // also hn (reuse)
    u16* qb  = (u16*)ws;             ws += MD * 2;       // qb..ao contiguous = ub [M,F]
    u16* kb  = (u16*)ws;             ws += MD * 2;
    u16* vb  = (u16*)ws;             ws += MD * 2;       // V^T [B][NH][DK][S]
    u16* ao  = (u16*)ws;             ws += MD * 2;
    float* hb = (float*)ws;          ws += MD * 4;
    u64* mb  = (u64*)ws;             ws += (size_t)BATCH * S_LEN * (S_LEN / 64) * 8;
    u16* hn = xn;
    u16* ub = qb;   // [M, F] bf16, reuses qb..ao (4*MD == M*F)
    (void)ws_size; (void)n_in; (void)in_sizes; (void)out_size;

    dim3 blk(256);

    prep<<<3200, blk, 0, stream>>>((const float4*)wq, (const float4*)wk, (const float4*)wv,
                                   (const float4*)wo, (const float4*)w1, (const float4*)w2,
                                   (const float4*)w3,
                                   (ushort4*)wqkvf, (ushort4*)wob, (ushort4*)w13f, (ushort4*)w2b,
                                   mask, mb, x, g_attn, xn);

    gemm_qkv<<<dim3(18, M_ROWS / 64), blk, 0, stream>>>(xn, wqkvf, qb, kb, vb);
    attn_mfma<<<dim3(S_LEN / 64, BATCH * NH), blk, 0, stream>>>(qb, kb, vb, mb, ao);
    gemm64<<<dim3(D_MODEL / 64, M_ROWS / 64), blk, 0, stream>>>(ao, wob, x, hb, D_MODEL, D_MODEL);
    rmsnorm_k<<<M_ROWS / 4, blk, 0, stream>>>((const float*)hb, g_ffn, hn);
    gemm_f1<<<dim3(24, M_ROWS / 64), blk, 0, stream>>>(hn, w13f, ub);
    gemm64<<<dim3(D_MODEL / 64, M_ROWS / 64), blk, 0, stream>>>(ub, w2b, hb, out, D_MODEL, F_DIM);
}

// Round 12
// 310.490 us; speedup vs baseline: 1.0588x; 1.0588x over previous
//
#include <hip/hip_runtime.h>
#include <hip/hip_bf16.h>

#define S_LEN 2048
#define D_MODEL 768
#define NH 12
#define DK 64
#define F_DIM 3072
#define BATCH 2
#define M_ROWS (BATCH * S_LEN)   // 4096

typedef __bf16 bf16x8 __attribute__((ext_vector_type(8)));
typedef float floatx4 __attribute__((ext_vector_type(4)));
typedef unsigned short u16;
typedef unsigned long long u64;

__device__ inline float bf2f(u16 u) {
    union { unsigned int i; float f; } x; x.i = ((unsigned int)u) << 16; return x.f;
}
__device__ inline u16 f2bf(float f) {
    union { float f; unsigned int i; } x; x.f = f;
    unsigned int r = x.i + 0x7fffu + ((x.i >> 16) & 1u);
    return (u16)(r >> 16);
}
__device__ __forceinline__ bf16x8 as_bf16x8(uint4 v) {
    union { uint4 u; bf16x8 b; } c; c.u = v; return c.b;
}

// async global->LDS, 16B per lane; LDS dest is wave-uniform base + lane*16
__device__ __forceinline__ void ldsload16(const u16* g, u16* l) {
    __builtin_amdgcn_global_load_lds(
        (const __attribute__((address_space(1))) unsigned int*)g,
        (__attribute__((address_space(3))) unsigned int*)l, 16, 0, 0);
}

// ---------------- merged preprocessing: cvt + mask_bits + rmsnorm1 ----------
// Round-10 config restored (best measured): many small blocks = TLP for these
// memory-bound fragments; grid-striding them regressed (round 11).
__device__ __forceinline__ void cvt_body(
        int i,
        const float4* wq, const float4* wk, const float4* wv, const float4* wo,
        const float4* w1, const float4* w2, const float4* w3,
        ushort4* wqkvf, ushort4* wob, ushort4* w13f, ushort4* w2b) {
    const int WS4 = (D_MODEL * D_MODEL) / 4;   // 147456
    const int WB4 = (F_DIM * D_MODEL) / 4;     // 589824
    const int RW4 = D_MODEL / 4;               // 192 float4 per row
    const float4* src; ushort4* dst; int off, doff;
    if (i < 4 * WS4) {
        int s = i / WS4; off = i - s * WS4;
        src = (s == 0) ? wq : (s == 1) ? wk : (s == 2) ? wv : wo;
        if (s == 3) { dst = wob; doff = off; }
        else {
            dst = wqkvf;
            int row = off / RW4, c4 = off - row * RW4;
            int k = c4 * 4;
            int rg = s * D_MODEL + row;          // global row 0..2303
            int n_tile = rg >> 4, nl = rg & 15;
            int k_tile = k >> 5, qd = (k >> 3) & 3, jj = k & 7;
            int ln = qd * 16 + nl;
            int f = n_tile * 24 + k_tile;
            doff = (f * 512 + ln * 8 + jj) >> 2;
        }
    } else {
        int j = i - 4 * WS4; int s = j / WB4; off = j - s * WB4;
        if (s == 1) { src = w2; dst = w2b; doff = off; }
        else {
            src = (s == 0) ? w1 : w3;
            dst = w13f;
            int which = (s == 0) ? 0 : 1;
            int row = off / RW4, c4 = off - row * RW4;
            int k = c4 * 4;
            int n_tile = row >> 4, nl = row & 15;
            int k_tile = k >> 5, qd = (k >> 3) & 3, jj = k & 7;
            int ln = qd * 16 + nl;
            int f = (n_tile * 24 + k_tile) * 2 + which;
            doff = (f * 512 + ln * 8 + jj) >> 2;
        }
    }
    float4 v = src[off];
    ushort4 o;
    o.x = f2bf(v.x); o.y = f2bf(v.y); o.z = f2bf(v.z); o.w = f2bf(v.w);
    dst[doff] = o;
}

__device__ __forceinline__ void mask_body(int bx, const int* m, u64* bits) {
    size_t base = (size_t)bx * 2048 + threadIdx.x;
    #pragma unroll
    for (int it = 0; it < 8; ++it) {
        size_t gid = base + (size_t)it * 256;
        u64 b = __ballot(m[gid] != 0);
        if ((threadIdx.x & 63) == 0) bits[gid >> 6] = b;
    }
}

__device__ __forceinline__ void rms_body(int row, const float* x, const float* g,
                                         u16* out, float* red) {
    const float* xr = x + (size_t)row * D_MODEL;
    u16* orow = out + (size_t)row * D_MODEL;
    int t = threadIdx.x;
    float v0 = xr[t];
    float v1 = xr[t + 256];
    float v2 = xr[t + 512];
    float ss = v0 * v0 + v1 * v1 + v2 * v2;
    #pragma unroll
    for (int off = 1; off < 64; off <<= 1) ss += __shfl_xor(ss, off);
    if ((t & 63) == 0) red[t >> 6] = ss;
    __syncthreads();
    float tot = red[0] + red[1] + red[2] + red[3];
    float scale = rsqrtf(tot * (1.0f / (float)D_MODEL) + 1e-5f);
    orow[t]       = f2bf(g[t]       * v0 * scale);
    orow[t + 256] = f2bf(g[t + 256] * v1 * scale);
    orow[t + 512] = f2bf(g[t + 512] * v2 * scale);
}

// grid = 9216 (cvt) + 4096 (mask) + 4096 (rms) = 17408 blocks
__global__ __launch_bounds__(256)
void prep(const float4* wq, const float4* wk, const float4* wv, const float4* wo,
          const float4* w1, const float4* w2, const float4* w3,
          ushort4* wqkvf, ushort4* wob, ushort4* w13f, ushort4* w2b,
          const int* m, u64* bits,
          const float* x, const float* g, u16* xn) {
    __shared__ float red[4];
    int bx = blockIdx.x;
    if (bx < 9216) {
        cvt_body(bx * 256 + threadIdx.x, wq, wk, wv, wo, w1, w2, w3,
                 wqkvf, wob, w13f, w2b);
    } else if (bx < 13312) {
        mask_body(bx - 9216, m, bits);
    } else {
        rms_body(bx - 13312, x, g, xn, red);
    }
}

// ---------------- RMSNorm standalone (for the h -> hn call) -----------------
__global__ __launch_bounds__(256)
void rmsnorm_k(const float* __restrict__ x, const float* __restrict__ g, u16* __restrict__ out) {
    __shared__ float red[4];
    rms_body(blockIdx.x, x, g, out, red);
}

// ---------------- FFN1: direct-global B-frags, A LDS-staged -----------------
// Block = 64m x 128out (4 waves, each 64m x 32out-pair). B-frags stream from
// global (L2) in fragment layout; XCD-swizzled grid keeps each XCD's weight
// slice L2-resident. C(bf16) = silu(A@w1^T) * (A@w3^T).
// v3: BK=64, 12 phases; B-frag loads issued before the barrier (latency
// overlaps the drain).
__global__ __launch_bounds__(256, 3)
void gemm_f1(const u16* __restrict__ A, const u16* __restrict__ W13f,
             u16* __restrict__ Cout) {
    const int K = D_MODEL, N = F_DIM;
    __shared__ u16 As[2][64][64];

    int t = threadIdx.x;
    int w = t >> 6, lane = t & 63;
    int lrow = lane & 15, quad = lane >> 4;

    int lid = blockIdx.y * 24 + blockIdx.x;
    int xcd = lid & 7, s = lid >> 3;          // 192 blocks per xcd
    int nb = xcd * 3 + (s % 3);               // 0..23
    int mb = s / 3;                           // 0..63
    int mBase = mb * 64;
    int ntile0 = nb * 8 + w * 2;              // wave's first n-tile

    int srow8 = lane >> 3;
    int sc64 = ((lane & 7) ^ srow8) * 8;
    const u16* Ag = A + (size_t)(mBase + w * 16 + srow8) * K + sc64;
    const uint4* Bf = (const uint4*)W13f;

    auto stageA = [&](int k0, int b) {
        ldsload16(Ag + k0,                 &As[b][w * 16][0]);
        ldsload16(Ag + (size_t)8 * K + k0, &As[b][w * 16 + 8][0]);
    };

    floatx4 zero = {0.f, 0.f, 0.f, 0.f};
    floatx4 acc[4][2], acc2[4][2];
    #pragma unroll
    for (int r = 0; r < 4; ++r)
        #pragma unroll
        for (int c = 0; c < 2; ++c) { acc[r][c] = zero; acc2[r][c] = zero; }

    stageA(0, 0);
    int cur = 0;
    for (int kt2 = 0; kt2 < 12; ++kt2) {
        uint4 b1v[2][2], b3v[2][2];
        #pragma unroll
        for (int hh = 0; hh < 2; ++hh) {
            int kt = kt2 * 2 + hh;
            #pragma unroll
            for (int c = 0; c < 2; ++c) {
                int f = ((ntile0 + c) * 24 + kt) * 2;
                b1v[hh][c] = Bf[(size_t)f * 64 + lane];
                b3v[hh][c] = Bf[(size_t)(f + 1) * 64 + lane];
            }
        }
        __syncthreads();                       // stageA(kt2) landed
        if (kt2 + 1 < 12) stageA((kt2 + 1) * 64, cur ^ 1);

        #pragma unroll
        for (int hh = 0; hh < 2; ++hh) {
            int rc = ((hh * 4 + quad) ^ (lrow & 7)) * 8;   // swizzled read col
            bf16x8 af[4];
            #pragma unroll
            for (int r = 0; r < 4; ++r) af[r] = *(const bf16x8*)&As[cur][r * 16 + lrow][rc];
            #pragma unroll
            for (int c = 0; c < 2; ++c) {
                bf16x8 b1f = as_bf16x8(b1v[hh][c]);
                bf16x8 b3f = as_bf16x8(b3v[hh][c]);
                #pragma unroll
                for (int r = 0; r < 4; ++r) {
                    acc[r][c]  = __builtin_amdgcn_mfma_f32_16x16x32_bf16(af[r], b1f, acc[r][c], 0, 0, 0);
                    acc2[r][c] = __builtin_amdgcn_mfma_f32_16x16x32_bf16(af[r], b3f, acc2[r][c], 0, 0, 0);
                }
            }
        }
        cur ^= 1;
    }

    #pragma unroll
    for (int r = 0; r < 4; ++r) {
        #pragma unroll
        for (int c = 0; c < 2; ++c) {
            #pragma unroll
            for (int j = 0; j < 4; ++j) {
                int grow = mBase + r * 16 + quad * 4 + j;
                int gcol = nb * 128 + w * 32 + c * 16 + lrow;
                float a = acc[r][c][j];
                Cout[(size_t)grow * N + gcol] = f2bf((a / (1.0f + __expf(-a))) * acc2[r][c][j]);
            }
        }
    }
}

// ---------------- 64x64-tile GEMM + residual (for N=768 GEMMs) --------------
// v4: BK=64 + xor-swizzle + per-XCD (mChunk x all-n) mapping.
__global__ __launch_bounds__(256, 3)
void gemm64(const u16* __restrict__ A, const u16* __restrict__ B1,
            const float* __restrict__ R, float* __restrict__ Cout, int N, int K) {
    __shared__ u16 As[2][64][64];
    __shared__ u16 Bs[2][64][64];

    int t = threadIdx.x;
    int w = t >> 6, lane = t & 63;

    int L = blockIdx.y * gridDim.x + blockIdx.x;
    int xcd = L & 7;
    int i = L >> 3;                         // 0..per-1
    int nT = gridDim.x;                     // n-tiles (12)
    int mPer = gridDim.y >> 3;              // m-tiles per XCD (8)
    int nIdx = i % nT;
    int mIdx = xcd * mPer + i / nT;
    int mBase = mIdx * 64, nBase = nIdx * 64;

    int lrow = lane & 15, quad = lane >> 4;
    int wm = (w >> 1) * 32, wn = (w & 1) * 32;

    int srow8 = lane >> 3;                          // 0..7
    int sc64 = ((lane & 7) ^ srow8) * 8;            // swizzled source col (elems)
    const u16* Ag = A  + (size_t)(mBase + w * 16 + srow8) * K + sc64;
    const u16* Bg = B1 + (size_t)(nBase + w * 16 + srow8) * K + sc64;

    auto stage = [&](int k0, int b) {
        ldsload16(Ag + k0,                 &As[b][w * 16][0]);
        ldsload16(Ag + (size_t)8 * K + k0, &As[b][w * 16 + 8][0]);
        ldsload16(Bg + k0,                 &Bs[b][w * 16][0]);
        ldsload16(Bg + (size_t)8 * K + k0, &Bs[b][w * 16 + 8][0]);
    };

    floatx4 zero = {0.f, 0.f, 0.f, 0.f};
    floatx4 acc[2][2];
    #pragma unroll
    for (int r = 0; r < 2; ++r)
        #pragma unroll
        for (int c = 0; c < 2; ++c) acc[r][c] = zero;

    stage(0, 0);
    int cur = 0;
    for (int k0 = 0; k0 < K; k0 += 64) {
        __syncthreads();
        if (k0 + 64 < K) stage(k0 + 64, cur ^ 1);

        #pragma unroll
        for (int half = 0; half < 2; ++half) {
            int rc = ((half * 4 + quad) ^ (lrow & 7)) * 8;   // swizzled read col
            bf16x8 af[2], bf[2];
            #pragma unroll
            for (int r = 0; r < 2; ++r) af[r] = *(const bf16x8*)&As[cur][wm + r * 16 + lrow][rc];
            #pragma unroll
            for (int c = 0; c < 2; ++c) bf[c] = *(const bf16x8*)&Bs[cur][wn + c * 16 + lrow][rc];
            #pragma unroll
            for (int r = 0; r < 2; ++r)
                #pragma unroll
                for (int c = 0; c < 2; ++c)
                    acc[r][c] = __builtin_amdgcn_mfma_f32_16x16x32_bf16(af[r], bf[c], acc[r][c], 0, 0, 0);
        }
        cur ^= 1;
    }

    #pragma unroll
    for (int r = 0; r < 2; ++r) {
        #pragma unroll
        for (int c = 0; c < 2; ++c) {
            #pragma unroll
            for (int j = 0; j < 4; ++j) {
                int grow = mBase + wm + r * 16 + quad * 4 + j;
                int gcol = nBase + wn + c * 16 + lrow;
                size_t idx = (size_t)grow * N + gcol;
                Cout[idx] = acc[r][c][j] + R[idx];
            }
        }
    }
}

// ---------------- fused QKV GEMM: f1-structure port -------------------------
// v5: V epilogue now LDS-transposes the 64x128 output sub-tile (reusing As)
// so V^T stores are coalesced 128B per instruction. The old path scattered
// 2B per lane at 4KB stride (one transaction per element, ~3.1M write
// transactions). Transpose region is wave-local (each wave writes and reads
// d in [w*32, w*32+32)) -> single barrier before As reuse, none after.
__global__ __launch_bounds__(256, 4)
void gemm_qkv(const u16* __restrict__ A, const u16* __restrict__ Wf,
              u16* __restrict__ qb, u16* __restrict__ kb, u16* __restrict__ vt) {
    const int K = D_MODEL;
    __shared__ u16 As[2][64][64];

    int t = threadIdx.x;
    int w = t >> 6, lane = t & 63;
    int lrow = lane & 15, quad = lane >> 4;

    int L = blockIdx.y * 18 + blockIdx.x;
    int g = (L & 7) * 144 + (L >> 3);            // 1152 blocks, 144 per XCD
    int nb = g >> 6;                              // 0..17 (128-col block)
    int mBase = (g & 63) * 64;
    int ntile0 = nb * 8 + w * 2;                  // wave's first n-tile (0..143)

    int srow8 = lane >> 3;
    int sc64 = ((lane & 7) ^ srow8) * 8;
    const u16* Ag = A + (size_t)(mBase + w * 16 + srow8) * K + sc64;
    const uint4* Bf = (const uint4*)Wf;

    auto stageA = [&](int k0, int b) {
        ldsload16(Ag + k0,                 &As[b][w * 16][0]);
        ldsload16(Ag + (size_t)8 * K + k0, &As[b][w * 16 + 8][0]);
    };

    floatx4 zero = {0.f, 0.f, 0.f, 0.f};
    floatx4 acc[4][2];
    #pragma unroll
    for (int r = 0; r < 4; ++r)
        #pragma unroll
        for (int c = 0; c < 2; ++c) acc[r][c] = zero;

    stageA(0, 0);
    int cur = 0;
    for (int kt2 = 0; kt2 < 12; ++kt2) {
        uint4 bv[2][2];
        #pragma unroll
        for (int hh = 0; hh < 2; ++hh) {
            int kt = kt2 * 2 + hh;
            #pragma unroll
            for (int c = 0; c < 2; ++c) {
                int f = (ntile0 + c) * 24 + kt;
                bv[hh][c] = Bf[(size_t)f * 64 + lane];
            }
        }
        __syncthreads();                       // stageA(kt2) landed
        if (kt2 + 1 < 12) stageA((kt2 + 1) * 64, cur ^ 1);

        #pragma unroll
        for (int hh = 0; hh < 2; ++hh) {
            int rc = ((hh * 4 + quad) ^ (lrow & 7)) * 8;   // swizzled read col
            bf16x8 af[4];
            #pragma unroll
            for (int r = 0; r < 4; ++r) af[r] = *(const bf16x8*)&As[cur][r * 16 + lrow][rc];
            #pragma unroll
            for (int c = 0; c < 2; ++c) {
                bf16x8 bfr = as_bf16x8(bv[hh][c]);
                #pragma unroll
                for (int r = 0; r < 4; ++r)
                    acc[r][c] = __builtin_amdgcn_mfma_f32_16x16x32_bf16(af[r], bfr, acc[r][c], 0, 0, 0);
            }
        }
        cur ^= 1;
    }

    const float qscale = 0.18033688011112042f;   // 0.125 * log2(e)
    int which = nb / 6;                           // all 128 cols same matrix
    if (which == 2) {
        // ---- V: LDS transpose (xor-swizzled rows) -> coalesced V^T stores --
        __syncthreads();                          // all waves done with As
        u16* T = &As[0][0][0];                    // [128][64] u16 = 16 KB
        int sc = (lrow & 7) << 3;                 // (d&7)<<3, d = w*32+c*16+lrow
        #pragma unroll
        for (int r = 0; r < 4; ++r)
            #pragma unroll
            for (int c = 0; c < 2; ++c) {
                int d = w * 32 + c * 16 + lrow;
                #pragma unroll
                for (int j = 0; j < 4; ++j) {
                    int s = r * 16 + quad * 4 + j;
                    T[d * 64 + (s ^ sc)] = f2bf(acc[r][c][j]);
                }
            }
        // wave-local: this wave reads exactly the d-rows it wrote.
        int bb = mBase >> 11, sbase = mBase & 2047;
        #pragma unroll
        for (int i = 0; i < 32; ++i) {
            int dl = w * 32 + i;
            u16 v = T[dl * 64 + (lane ^ ((i & 7) << 3))];
            int cm = nb * 128 + dl - 2 * D_MODEL;   // col within V matrix
            int hh = cm >> 6, dd = cm & 63;
            vt[((((size_t)bb * NH + hh) * DK + dd) << 11) + sbase + lane] = v;
        }
    } else {
        u16* dst = (which == 0) ? qb : kb;
        #pragma unroll
        for (int r = 0; r < 4; ++r) {
            #pragma unroll
            for (int c = 0; c < 2; ++c) {
                #pragma unroll
                for (int j = 0; j < 4; ++j) {
                    int grow = mBase + r * 16 + quad * 4 + j;
                    int gcol = nb * 128 + w * 32 + c * 16 + lrow;   // 0..2303
                    int cm = gcol - which * D_MODEL;                // col in matrix
                    float val = acc[r][c][j];
                    if (which == 0) val *= qscale;
                    dst[(size_t)grow * D_MODEL + cm] = f2bf(val);
                }
            }
        }
    }
}

// ---------------- MFMA flash attention (S^T formulation) --------------------
// v9: K/V xor-swizzled LDS, Q in regs, PT cg-xor swizzled (40960B LDS),
// XCD-grouped blocks (K/V L2-resident). Floored at ~60us (grid = 3 blocks/CU
// exactly; issue/latency-bound, no pipe saturated).
__global__ __launch_bounds__(256)
void attn_mfma(const u16* __restrict__ q, const u16* __restrict__ k,
               const u16* __restrict__ vt, const u64* __restrict__ mbits,
               u16* __restrict__ out) {
    __shared__ u16 Ks0[2][64][32], Ks1[2][64][32];
    __shared__ u16 Vs0[2][64][32], Vs1[2][64][32];
    __shared__ u16 PT[4][16][64];     // per-wave P^T, cg-xor swizzled

    int t = threadIdx.x;
    int lane = t & 63;
    int w = t >> 6;
    int lrow = lane & 15;
    int quad = lane >> 4;

    // XCD swizzle: 768 blocks, 96/XCD = 3 bh-groups x 32 q-tiles
    int L = blockIdx.y * gridDim.x + blockIdx.x;   // gridDim.x = 32
    int g = (L & 7) * 96 + (L >> 3);
    int st0 = (g & 31) * 64;
    int bh = g >> 5;
    int h = bh % NH;
    int b = bh / NH;

    const u16* kbase = k + (size_t)b * S_LEN * D_MODEL + h * DK;
    const u16* vbase = vt + (size_t)bh * DK * S_LEN;
    const u64* bw = mbits + ((size_t)b * S_LEN + st0 + w * 16 + lrow) * (S_LEN / 64);

    int srow = lane >> 2;          // staging row within 16-row chunk
    int scolS = ((lane & 3) ^ ((lane >> 3) & 3)) * 8;   // staging source col
    int rq = (quad ^ ((lrow >> 1) & 3)) * 8;            // swizzled read col
    // PT swizzle terms (per-thread constants)
    int ptw = lrow & 7;
    int rp0 = (quad ^ ptw) * 8;           // logical cg = quad
    int rp1 = ((4 + quad) ^ ptw) * 8;     // logical cg = 4+quad
    int pqo = (quad & 1) * 4;             // uint2 sub-offset within group
    int pch = quad >> 1;

    const u16* kg = kbase + (size_t)(w * 16 + srow) * D_MODEL + scolS;
    const u16* vg = vbase + (size_t)(w * 16 + srow) * S_LEN + scolS;

    auto stageKV = [&](int kt, int bsel) {
        ldsload16(kg + (size_t)kt * D_MODEL,      &Ks0[bsel][w * 16][0]);
        ldsload16(kg + (size_t)kt * D_MODEL + 32, &Ks1[bsel][w * 16][0]);
        ldsload16(vg + kt,      &Vs0[bsel][w * 16][0]);
        ldsload16(vg + kt + 32, &Vs1[bsel][w * 16][0]);
    };

    stageKV(0, 0);

    // ---- Q fragments direct from global into regs (once per block) ----
    bf16x8 bq0, bq1;
    {
        const u16* qrow = q + ((size_t)b * S_LEN + st0 + w * 16 + lrow) * D_MODEL + h * DK + quad * 8;
        bq0 = *(const bf16x8*)qrow;
        bq1 = *(const bf16x8*)(qrow + 32);
    }

    // ones vector (bf16 1.0 x8) for MFMA row-sums
    bf16x8 ones;
    {
        union { u16 u; __bf16 b; } o; o.u = 0x3F80;
        #pragma unroll
        for (int j = 0; j < 8; ++j) ones[j] = o.b;
    }

    floatx4 zero = {0.f, 0.f, 0.f, 0.f};
    floatx4 Ot[4] = {zero, zero, zero, zero};
    floatx4 Osum = zero;              // row-sums of P (per-lane rows quad*4+j)

    u64 mw = bw[0];                   // mask bits for tile 0 (prefetched)
    __syncthreads();                  // stageKV(0) landed

    int cur = 0;
    for (int kt = 0; kt < S_LEN; kt += 64) {
        // prefetch next K/V tile -> other LDS buffer, mask word -> reg
        if (kt + 64 < S_LEN) stageKV(kt + 64, cur ^ 1);
        u64 mw_next = (kt + 64 < S_LEN) ? bw[(kt >> 6) + 1] : 0ull;
        unsigned mlo = (unsigned)mw, mhi = (unsigned)(mw >> 32);

        // --- S^T = K Q^T : 64 keys x 16 q per wave ---
        floatx4 st[4];
        #pragma unroll
        for (int nt = 0; nt < 4; ++nt) {
            bf16x8 ak0 = *(const bf16x8*)&Ks0[cur][nt * 16 + lrow][rq];
            bf16x8 ak1 = *(const bf16x8*)&Ks1[cur][nt * 16 + lrow][rq];
            st[nt] = __builtin_amdgcn_mfma_f32_16x16x32_bf16(ak0, bq0, zero, 0, 0, 0);
            st[nt] = __builtin_amdgcn_mfma_f32_16x16x32_bf16(ak1, bq1, st[nt], 0, 0, 0);
        }

        // --- P^T = maskbit * exp2(S^T), truncated to bf16, packed writes ---
        #pragma unroll
        for (int nt = 0; nt < 4; ++nt) {
            unsigned half = (nt & 2) ? mhi : mlo;
            unsigned tmp = half >> ((nt & 1) * 16 + quad * 4);
            unsigned eu[4];
            #pragma unroll
            for (int j = 0; j < 4; ++j) {
                float e = __builtin_amdgcn_exp2f(st[nt][j]);
                unsigned msk = (unsigned)((int)(tmp << (31 - j)) >> 31);
                eu[j] = __float_as_uint(e) & msk;
            }
            uint2 p;
            p.x = (eu[0] >> 16) | (eu[1] & 0xffff0000u);
            p.y = (eu[2] >> 16) | (eu[3] & 0xffff0000u);
            // logical col = nt*16 + quad*4 -> cg = nt*2 + (quad>>1)
            int pc = ((nt * 2 + pch) ^ ptw) * 8 + pqo;
            *(uint2*)&PT[w][lrow][pc] = p;
        }

        // --- O += P V ; row-sums += P * ones (on the MFMA pipe) ---
        bf16x8 ap0 = *(const bf16x8*)&PT[w][lrow][rp0];
        bf16x8 ap1 = *(const bf16x8*)&PT[w][lrow][rp1];
        Osum = __builtin_amdgcn_mfma_f32_16x16x32_bf16(ap0, ones, Osum, 0, 0, 0);
        Osum = __builtin_amdgcn_mfma_f32_16x16x32_bf16(ap1, ones, Osum, 0, 0, 0);
        #pragma unroll
        for (int dt = 0; dt < 4; ++dt) {
            bf16x8 bv0 = *(const bf16x8*)&Vs0[cur][dt * 16 + lrow][rq];
            bf16x8 bv1 = *(const bf16x8*)&Vs1[cur][dt * 16 + lrow][rq];
            Ot[dt] = __builtin_amdgcn_mfma_f32_16x16x32_bf16(ap0, bv0, Ot[dt], 0, 0, 0);
            Ot[dt] = __builtin_amdgcn_mfma_f32_16x16x32_bf16(ap1, bv1, Ot[dt], 0, 0, 0);
        }

        // single barrier per tile: all waves done reading buf[cur] (so next
        // iter may overwrite) and stageKV(kt+64) landed (vmcnt drain).
        __syncthreads();
        cur ^= 1;
        mw = mw_next;
    }

    // --- Osum[j] is the row-sum for q-row quad*4+j (cols identical) ---
    float invj[4];
    #pragma unroll
    for (int j = 0; j < 4; ++j) invj[j] = 1.0f / Osum[j];

    u16* obase = out + ((size_t)b * S_LEN + st0 + w * 16) * D_MODEL + h * DK;
    #pragma unroll
    for (int dt = 0; dt < 4; ++dt)
        #pragma unroll
        for (int j = 0; j < 4; ++j)
            obase[(size_t)(quad * 4 + j) * D_MODEL + dt * 16 + lrow] = f2bf(Ot[dt][j] * invj[j]);
}

// ---------------- host launch ----------------
extern "C" void kernel_launch(void* const* d_in, const int* in_sizes, int n_in,
                              void* d_out, int out_size, void* d_ws, size_t ws_size,
                              hipStream_t stream) {
    const float* x      = (const float*)d_in[0];
    const int*   mask   = (const int*)d_in[1];
    const float* wq     = (const float*)d_in[2];
    const float* wk     = (const float*)d_in[3];
    const float* wv     = (const float*)d_in[4];
    const float* wo     = (const float*)d_in[5];
    const float* w1     = (const float*)d_in[6];
    const float* w2     = (const float*)d_in[7];
    const float* w3     = (const float*)d_in[8];
    const float* g_attn = (const float*)d_in[9];
    const float* g_ffn  = (const float*)d_in[10];
    float* out = (float*)d_out;

    const size_t WSMALL = (size_t)D_MODEL * D_MODEL;
    const size_t WBIG   = (size_t)F_DIM * D_MODEL;
    const size_t MD     = (size_t)M_ROWS * D_MODEL;

    char* ws = (char*)d_ws;
    u16* wqkvf = (u16*)ws;           ws += WSMALL * 3 * 2;  // frag-ordered wq|wk|wv
    u16* wob  = (u16*)ws;            ws += WSMALL * 2;
    u16* w13f = (u16*)ws;            ws += WBIG * 2 * 2;   // frag-ordered w1|w3
    u16* w2b  = (u16*)ws;            ws += WBIG * 2;
    u16* xn  = (u16*)ws;             ws += MD * 2;       // also hn (reuse)
    u16* qb  = (u16*)ws;             ws += MD * 2;       // qb..ao contiguous = ub [M,F]
    u16* kb  = (u16*)ws;             ws += MD * 2;
    u16* vb  = (u16*)ws;             ws += MD * 2;       // V^T [B][NH][DK][S]
    u16* ao  = (u16*)ws;             ws += MD * 2;
    float* hb = (float*)ws;          ws += MD * 4;
    u64* mb  = (u64*)ws;             ws += (size_t)BATCH * S_LEN * (S_LEN / 64) * 8;
    u16* hn = xn;
    u16* ub = qb;   // [M, F] bf16, reuses qb..ao (4*MD == M*F)
    (void)ws_size; (void)n_in; (void)in_sizes; (void)out_size;

    dim3 blk(256);

    prep<<<17408, blk, 0, stream>>>((const float4*)wq, (const float4*)wk, (const float4*)wv,
                                    (const float4*)wo, (const float4*)w1, (const float4*)w2,
                                    (const float4*)w3,
                                    (ushort4*)wqkvf, (ushort4*)wob, (ushort4*)w13f, (ushort4*)w2b,
                                    mask, mb, x, g_attn, xn);

    gemm_qkv<<<dim3(18, M_ROWS / 64), blk, 0, stream>>>(xn, wqkvf, qb, kb, vb);
    attn_mfma<<<dim3(S_LEN / 64, BATCH * NH), blk, 0, stream>>>(qb, kb, vb, mb, ao);
    gemm64<<<dim3(D_MODEL / 64, M_ROWS / 64), blk, 0, stream>>>(ao, wob, x, hb, D_MODEL, D_MODEL);
    rmsnorm_k<<<M_ROWS, blk, 0, stream>>>((const float*)hb, g_ffn, hn);
    gemm_f1<<<dim3(24, M_ROWS / 64), blk, 0, stream>>>(hn, w13f, ub);
    gemm64<<<dim3(D_MODEL / 64, M_ROWS / 64), blk, 0, stream>>>(ub, w2b, hb, out, D_MODEL, F_DIM);
}

// Round 13
// 304.222 us; speedup vs baseline: 1.0806x; 1.0206x over previous
//
#include <hip/hip_runtime.h>
#include <hip/hip_bf16.h>

#define S_LEN 2048
#define D_MODEL 768
#define NH 12
#define DK 64
#define F_DIM 3072
#define BATCH 2
#define M_ROWS (BATCH * S_LEN)   // 4096

typedef __bf16 bf16x8 __attribute__((ext_vector_type(8)));
typedef float floatx4 __attribute__((ext_vector_type(4)));
typedef unsigned short u16;
typedef unsigned long long u64;

__device__ inline float bf2f(u16 u) {
    union { unsigned int i; float f; } x; x.i = ((unsigned int)u) << 16; return x.f;
}
__device__ inline u16 f2bf(float f) {
    union { float f; unsigned int i; } x; x.f = f;
    unsigned int r = x.i + 0x7fffu + ((x.i >> 16) & 1u);
    return (u16)(r >> 16);
}
__device__ __forceinline__ bf16x8 as_bf16x8(uint4 v) {
    union { uint4 u; bf16x8 b; } c; c.u = v; return c.b;
}

// async global->LDS, 16B per lane; LDS dest is wave-uniform base + lane*16
__device__ __forceinline__ void ldsload16(const u16* g, u16* l) {
    __builtin_amdgcn_global_load_lds(
        (const __attribute__((address_space(1))) unsigned int*)g,
        (__attribute__((address_space(3))) unsigned int*)l, 16, 0, 0);
}

// ---------------- merged preprocessing: cvt + mask_bits + rmsnorm1 ----------
__device__ __forceinline__ void cvt_body(
        int i,
        const float4* wq, const float4* wk, const float4* wv, const float4* wo,
        const float4* w1, const float4* w2, const float4* w3,
        ushort4* wqkvf, ushort4* wob, ushort4* w13f, ushort4* w2b) {
    const int WS4 = (D_MODEL * D_MODEL) / 4;   // 147456
    const int WB4 = (F_DIM * D_MODEL) / 4;     // 589824
    const int RW4 = D_MODEL / 4;               // 192 float4 per row
    const float4* src; ushort4* dst; int off, doff;
    if (i < 4 * WS4) {
        int s = i / WS4; off = i - s * WS4;
        src = (s == 0) ? wq : (s == 1) ? wk : (s == 2) ? wv : wo;
        if (s == 3) { dst = wob; doff = off; }
        else {
            dst = wqkvf;
            int row = off / RW4, c4 = off - row * RW4;
            int k = c4 * 4;
            int rg = s * D_MODEL + row;          // global row 0..2303
            int n_tile = rg >> 4, nl = rg & 15;
            int k_tile = k >> 5, qd = (k >> 3) & 3, jj = k & 7;
            int ln = qd * 16 + nl;
            int f = n_tile * 24 + k_tile;
            doff = (f * 512 + ln * 8 + jj) >> 2;
        }
    } else {
        int j = i - 4 * WS4; int s = j / WB4; off = j - s * WB4;
        if (s == 1) { src = w2; dst = w2b; doff = off; }
        else {
            src = (s == 0) ? w1 : w3;
            dst = w13f;
            int which = (s == 0) ? 0 : 1;
            int row = off / RW4, c4 = off - row * RW4;
            int k = c4 * 4;
            int n_tile = row >> 4, nl = row & 15;
            int k_tile = k >> 5, qd = (k >> 3) & 3, jj = k & 7;
            int ln = qd * 16 + nl;
            int f = (n_tile * 24 + k_tile) * 2 + which;
            doff = (f * 512 + ln * 8 + jj) >> 2;
        }
    }
    float4 v = src[off];
    ushort4 o;
    o.x = f2bf(v.x); o.y = f2bf(v.y); o.z = f2bf(v.z); o.w = f2bf(v.w);
    dst[doff] = o;
}

__device__ __forceinline__ void mask_body(int bx, const int* m, u64* bits) {
    size_t base = (size_t)bx * 2048 + threadIdx.x;
    #pragma unroll
    for (int it = 0; it < 8; ++it) {
        size_t gid = base + (size_t)it * 256;
        u64 b = __ballot(m[gid] != 0);
        if ((threadIdx.x & 63) == 0) bits[gid >> 6] = b;
    }
}

__device__ __forceinline__ void rms_body(int row, const float* x, const float* g,
                                         u16* out, float* red) {
    const float* xr = x + (size_t)row * D_MODEL;
    u16* orow = out + (size_t)row * D_MODEL;
    int t = threadIdx.x;
    float v0 = xr[t];
    float v1 = xr[t + 256];
    float v2 = xr[t + 512];
    float ss = v0 * v0 + v1 * v1 + v2 * v2;
    #pragma unroll
    for (int off = 1; off < 64; off <<= 1) ss += __shfl_xor(ss, off);
    if ((t & 63) == 0) red[t >> 6] = ss;
    __syncthreads();
    float tot = red[0] + red[1] + red[2] + red[3];
    float scale = rsqrtf(tot * (1.0f / (float)D_MODEL) + 1e-5f);
    orow[t]       = f2bf(g[t]       * v0 * scale);
    orow[t + 256] = f2bf(g[t + 256] * v1 * scale);
    orow[t + 512] = f2bf(g[t + 512] * v2 * scale);
}

// grid = 9216 (cvt) + 4096 (mask) + 4096 (rms) = 17408 blocks
__global__ __launch_bounds__(256)
void prep(const float4* wq, const float4* wk, const float4* wv, const float4* wo,
          const float4* w1, const float4* w2, const float4* w3,
          ushort4* wqkvf, ushort4* wob, ushort4* w13f, ushort4* w2b,
          const int* m, u64* bits,
          const float* x, const float* g, u16* xn) {
    __shared__ float red[4];
    int bx = blockIdx.x;
    if (bx < 9216) {
        cvt_body(bx * 256 + threadIdx.x, wq, wk, wv, wo, w1, w2, w3,
                 wqkvf, wob, w13f, w2b);
    } else if (bx < 13312) {
        mask_body(bx - 9216, m, bits);
    } else {
        rms_body(bx - 13312, x, g, xn, red);
    }
}

// ---------------- RMSNorm standalone (for the h -> hn call) -----------------
__global__ __launch_bounds__(256)
void rmsnorm_k(const float* __restrict__ x, const float* __restrict__ g, u16* __restrict__ out) {
    __shared__ float red[4];
    rms_body(blockIdx.x, x, g, out, red);
}

// ---------------- FFN1: direct-global B-frags, A LDS-staged -----------------
// v3: BK=64, 12 phases; B-frag loads issued before the barrier (latency
// overlaps the drain).
__global__ __launch_bounds__(256, 3)
void gemm_f1(const u16* __restrict__ A, const u16* __restrict__ W13f,
             u16* __restrict__ Cout) {
    const int K = D_MODEL, N = F_DIM;
    __shared__ u16 As[2][64][64];

    int t = threadIdx.x;
    int w = t >> 6, lane = t & 63;
    int lrow = lane & 15, quad = lane >> 4;

    int lid = blockIdx.y * 24 + blockIdx.x;
    int xcd = lid & 7, s = lid >> 3;          // 192 blocks per xcd
    int nb = xcd * 3 + (s % 3);               // 0..23
    int mb = s / 3;                           // 0..63
    int mBase = mb * 64;
    int ntile0 = nb * 8 + w * 2;              // wave's first n-tile

    int srow8 = lane >> 3;
    int sc64 = ((lane & 7) ^ srow8) * 8;
    const u16* Ag = A + (size_t)(mBase + w * 16 + srow8) * K + sc64;
    const uint4* Bf = (const uint4*)W13f;

    auto stageA = [&](int k0, int b) {
        ldsload16(Ag + k0,                 &As[b][w * 16][0]);
        ldsload16(Ag + (size_t)8 * K + k0, &As[b][w * 16 + 8][0]);
    };

    floatx4 zero = {0.f, 0.f, 0.f, 0.f};
    floatx4 acc[4][2], acc2[4][2];
    #pragma unroll
    for (int r = 0; r < 4; ++r)
        #pragma unroll
        for (int c = 0; c < 2; ++c) { acc[r][c] = zero; acc2[r][c] = zero; }

    stageA(0, 0);
    int cur = 0;
    for (int kt2 = 0; kt2 < 12; ++kt2) {
        uint4 b1v[2][2], b3v[2][2];
        #pragma unroll
        for (int hh = 0; hh < 2; ++hh) {
            int kt = kt2 * 2 + hh;
            #pragma unroll
            for (int c = 0; c < 2; ++c) {
                int f = ((ntile0 + c) * 24 + kt) * 2;
                b1v[hh][c] = Bf[(size_t)f * 64 + lane];
                b3v[hh][c] = Bf[(size_t)(f + 1) * 64 + lane];
            }
        }
        __syncthreads();                       // stageA(kt2) landed
        if (kt2 + 1 < 12) stageA((kt2 + 1) * 64, cur ^ 1);

        #pragma unroll
        for (int hh = 0; hh < 2; ++hh) {
            int rc = ((hh * 4 + quad) ^ (lrow & 7)) * 8;   // swizzled read col
            bf16x8 af[4];
            #pragma unroll
            for (int r = 0; r < 4; ++r) af[r] = *(const bf16x8*)&As[cur][r * 16 + lrow][rc];
            #pragma unroll
            for (int c = 0; c < 2; ++c) {
                bf16x8 b1f = as_bf16x8(b1v[hh][c]);
                bf16x8 b3f = as_bf16x8(b3v[hh][c]);
                #pragma unroll
                for (int r = 0; r < 4; ++r) {
                    acc[r][c]  = __builtin_amdgcn_mfma_f32_16x16x32_bf16(af[r], b1f, acc[r][c], 0, 0, 0);
                    acc2[r][c] = __builtin_amdgcn_mfma_f32_16x16x32_bf16(af[r], b3f, acc2[r][c], 0, 0, 0);
                }
            }
        }
        cur ^= 1;
    }

    #pragma unroll
    for (int r = 0; r < 4; ++r) {
        #pragma unroll
        for (int c = 0; c < 2; ++c) {
            #pragma unroll
            for (int j = 0; j < 4; ++j) {
                int grow = mBase + r * 16 + quad * 4 + j;
                int gcol = nb * 128 + w * 32 + c * 16 + lrow;
                float a = acc[r][c][j];
                Cout[(size_t)grow * N + gcol] = f2bf((a / (1.0f + __expf(-a))) * acc2[r][c][j]);
            }
        }
    }
}

// ---------------- 64x64-tile GEMM + residual (for N=768 GEMMs) --------------
// v5: per-XCD mapping with m cycling FASTEST within each XCD (was n-fastest).
// Each B-panel (64 x K) is now reused by 8 consecutive co-resident blocks
// (L2-hit) while the XCD's A-slice (8 m-tiles) stays L2-resident: per-XCD
// working set = A-slice + 1 B-panel (K=3072: 3.1 MB + 0.4 MB < 4 MB L2).
// Old order re-fetched each B-panel per m-tile: ~250 MB of L2-miss traffic
// on the FFN2 call (K=3072), exposed at every one of 48 barrier drains.
__global__ __launch_bounds__(256, 3)
void gemm64(const u16* __restrict__ A, const u16* __restrict__ B1,
            const float* __restrict__ R, float* __restrict__ Cout, int N, int K) {
    __shared__ u16 As[2][64][64];
    __shared__ u16 Bs[2][64][64];

    int t = threadIdx.x;
    int w = t >> 6, lane = t & 63;

    int L = blockIdx.y * gridDim.x + blockIdx.x;
    int xcd = L & 7;
    int i = L >> 3;                         // 0..per-1
    int mPer = gridDim.y >> 3;              // m-tiles per XCD (8)
    int nIdx = i / mPer;                    // n cycles SLOWEST
    int mIdx = xcd * mPer + i % mPer;       // m cycles fastest within XCD
    int mBase = mIdx * 64, nBase = nIdx * 64;

    int lrow = lane & 15, quad = lane >> 4;
    int wm = (w >> 1) * 32, wn = (w & 1) * 32;

    int srow8 = lane >> 3;                          // 0..7
    int sc64 = ((lane & 7) ^ srow8) * 8;            // swizzled source col (elems)
    const u16* Ag = A  + (size_t)(mBase + w * 16 + srow8) * K + sc64;
    const u16* Bg = B1 + (size_t)(nBase + w * 16 + srow8) * K + sc64;

    auto stage = [&](int k0, int b) {
        ldsload16(Ag + k0,                 &As[b][w * 16][0]);
        ldsload16(Ag + (size_t)8 * K + k0, &As[b][w * 16 + 8][0]);
        ldsload16(Bg + k0,                 &Bs[b][w * 16][0]);
        ldsload16(Bg + (size_t)8 * K + k0, &Bs[b][w * 16 + 8][0]);
    };

    floatx4 zero = {0.f, 0.f, 0.f, 0.f};
    floatx4 acc[2][2];
    #pragma unroll
    for (int r = 0; r < 2; ++r)
        #pragma unroll
        for (int c = 0; c < 2; ++c) acc[r][c] = zero;

    stage(0, 0);
    int cur = 0;
    for (int k0 = 0; k0 < K; k0 += 64) {
        __syncthreads();
        if (k0 + 64 < K) stage(k0 + 64, cur ^ 1);

        #pragma unroll
        for (int half = 0; half < 2; ++half) {
            int rc = ((half * 4 + quad) ^ (lrow & 7)) * 8;   // swizzled read col
            bf16x8 af[2], bf[2];
            #pragma unroll
            for (int r = 0; r < 2; ++r) af[r] = *(const bf16x8*)&As[cur][wm + r * 16 + lrow][rc];
            #pragma unroll
            for (int c = 0; c < 2; ++c) bf[c] = *(const bf16x8*)&Bs[cur][wn + c * 16 + lrow][rc];
            #pragma unroll
            for (int r = 0; r < 2; ++r)
                #pragma unroll
                for (int c = 0; c < 2; ++c)
                    acc[r][c] = __builtin_amdgcn_mfma_f32_16x16x32_bf16(af[r], bf[c], acc[r][c], 0, 0, 0);
        }
        cur ^= 1;
    }

    #pragma unroll
    for (int r = 0; r < 2; ++r) {
        #pragma unroll
        for (int c = 0; c < 2; ++c) {
            #pragma unroll
            for (int j = 0; j < 4; ++j) {
                int grow = mBase + wm + r * 16 + quad * 4 + j;
                int gcol = nBase + wn + c * 16 + lrow;
                size_t idx = (size_t)grow * N + gcol;
                Cout[idx] = acc[r][c][j] + R[idx];
            }
        }
    }
}

// ---------------- fused QKV GEMM: f1-structure port -------------------------
// v5: V epilogue LDS-transposes the output sub-tile for coalesced V^T stores.
__global__ __launch_bounds__(256, 4)
void gemm_qkv(const u16* __restrict__ A, const u16* __restrict__ Wf,
              u16* __restrict__ qb, u16* __restrict__ kb, u16* __restrict__ vt) {
    const int K = D_MODEL;
    __shared__ u16 As[2][64][64];

    int t = threadIdx.x;
    int w = t >> 6, lane = t & 63;
    int lrow = lane & 15, quad = lane >> 4;

    int L = blockIdx.y * 18 + blockIdx.x;
    int g = (L & 7) * 144 + (L >> 3);            // 1152 blocks, 144 per XCD
    int nb = g >> 6;                              // 0..17 (128-col block)
    int mBase = (g & 63) * 64;
    int ntile0 = nb * 8 + w * 2;                  // wave's first n-tile (0..143)

    int srow8 = lane >> 3;
    int sc64 = ((lane & 7) ^ srow8) * 8;
    const u16* Ag = A + (size_t)(mBase + w * 16 + srow8) * K + sc64;
    const uint4* Bf = (const uint4*)Wf;

    auto stageA = [&](int k0, int b) {
        ldsload16(Ag + k0,                 &As[b][w * 16][0]);
        ldsload16(Ag + (size_t)8 * K + k0, &As[b][w * 16 + 8][0]);
    };

    floatx4 zero = {0.f, 0.f, 0.f, 0.f};
    floatx4 acc[4][2];
    #pragma unroll
    for (int r = 0; r < 4; ++r)
        #pragma unroll
        for (int c = 0; c < 2; ++c) acc[r][c] = zero;

    stageA(0, 0);
    int cur = 0;
    for (int kt2 = 0; kt2 < 12; ++kt2) {
        uint4 bv[2][2];
        #pragma unroll
        for (int hh = 0; hh < 2; ++hh) {
            int kt = kt2 * 2 + hh;
            #pragma unroll
            for (int c = 0; c < 2; ++c) {
                int f = (ntile0 + c) * 24 + kt;
                bv[hh][c] = Bf[(size_t)f * 64 + lane];
            }
        }
        __syncthreads();                       // stageA(kt2) landed
        if (kt2 + 1 < 12) stageA((kt2 + 1) * 64, cur ^ 1);

        #pragma unroll
        for (int hh = 0; hh < 2; ++hh) {
            int rc = ((hh * 4 + quad) ^ (lrow & 7)) * 8;   // swizzled read col
            bf16x8 af[4];
            #pragma unroll
            for (int r = 0; r < 4; ++r) af[r] = *(const bf16x8*)&As[cur][r * 16 + lrow][rc];
            #pragma unroll
            for (int c = 0; c < 2; ++c) {
                bf16x8 bfr = as_bf16x8(bv[hh][c]);
                #pragma unroll
                for (int r = 0; r < 4; ++r)
                    acc[r][c] = __builtin_amdgcn_mfma_f32_16x16x32_bf16(af[r], bfr, acc[r][c], 0, 0, 0);
            }
        }
        cur ^= 1;
    }

    const float qscale = 0.18033688011112042f;   // 0.125 * log2(e)
    int which = nb / 6;                           // all 128 cols same matrix
    if (which == 2) {
        // ---- V: LDS transpose (xor-swizzled rows) -> coalesced V^T stores --
        __syncthreads();                          // all waves done with As
        u16* T = &As[0][0][0];                    // [128][64] u16 = 16 KB
        #pragma unroll
        for (int r = 0; r < 4; ++r)
            #pragma unroll
            for (int c = 0; c < 2; ++c) {
                int d = w * 32 + c * 16 + lrow;
                int sc = (d & 7) << 3;
                #pragma unroll
                for (int j = 0; j < 4; ++j) {
                    int s = r * 16 + quad * 4 + j;
                    T[d * 64 + (s ^ sc)] = f2bf(acc[r][c][j]);
                }
            }
        // wave-local: this wave reads exactly the d-rows it wrote.
        int bb = mBase >> 11, sbase = mBase & 2047;
        #pragma unroll
        for (int i = 0; i < 32; ++i) {
            int dl = w * 32 + i;
            u16 v = T[dl * 64 + (lane ^ ((dl & 7) << 3))];
            int cm = nb * 128 + dl - 2 * D_MODEL;   // col within V matrix
            int hh = cm >> 6, dd = cm & 63;
            vt[((((size_t)bb * NH + hh) * DK + dd) << 11) + sbase + lane] = v;
        }
    } else {
        u16* dst = (which == 0) ? qb : kb;
        #pragma unroll
        for (int r = 0; r < 4; ++r) {
            #pragma unroll
            for (int c = 0; c < 2; ++c) {
                #pragma unroll
                for (int j = 0; j < 4; ++j) {
                    int grow = mBase + r * 16 + quad * 4 + j;
                    int gcol = nb * 128 + w * 32 + c * 16 + lrow;   // 0..2303
                    int cm = gcol - which * D_MODEL;                // col in matrix
                    float val = acc[r][c][j];
                    if (which == 0) val *= qscale;
                    dst[(size_t)grow * D_MODEL + cm] = f2bf(val);
                }
            }
        }
    }
}

// ---------------- MFMA flash attention (S^T formulation) --------------------
// v9: K/V xor-swizzled LDS, Q in regs, PT cg-xor swizzled (40960B LDS),
// XCD-grouped blocks (K/V L2-resident). Floored at ~60us (grid = 3 blocks/CU
// exactly; issue/latency-bound, no pipe saturated).
__global__ __launch_bounds__(256)
void attn_mfma(const u16* __restrict__ q, const u16* __restrict__ k,
               const u16* __restrict__ vt, const u64* __restrict__ mbits,
               u16* __restrict__ out) {
    __shared__ u16 Ks0[2][64][32], Ks1[2][64][32];
    __shared__ u16 Vs0[2][64][32], Vs1[2][64][32];
    __shared__ u16 PT[4][16][64];     // per-wave P^T, cg-xor swizzled

    int t = threadIdx.x;
    int lane = t & 63;
    int w = t >> 6;
    int lrow = lane & 15;
    int quad = lane >> 4;

    // XCD swizzle: 768 blocks, 96/XCD = 3 bh-groups x 32 q-tiles
    int L = blockIdx.y * gridDim.x + blockIdx.x;   // gridDim.x = 32
    int g = (L & 7) * 96 + (L >> 3);
    int st0 = (g & 31) * 64;
    int bh = g >> 5;
    int h = bh % NH;
    int b = bh / NH;

    const u16* kbase = k + (size_t)b * S_LEN * D_MODEL + h * DK;
    const u16* vbase = vt + (size_t)bh * DK * S_LEN;
    const u64* bw = mbits + ((size_t)b * S_LEN + st0 + w * 16 + lrow) * (S_LEN / 64);

    int srow = lane >> 2;          // staging row within 16-row chunk
    int scolS = ((lane & 3) ^ ((lane >> 3) & 3)) * 8;   // staging source col
    int rq = (quad ^ ((lrow >> 1) & 3)) * 8;            // swizzled read col
    // PT swizzle terms (per-thread constants)
    int ptw = lrow & 7;
    int rp0 = (quad ^ ptw) * 8;           // logical cg = quad
    int rp1 = ((4 + quad) ^ ptw) * 8;     // logical cg = 4+quad
    int pqo = (quad & 1) * 4;             // uint2 sub-offset within group
    int pch = quad >> 1;

    const u16* kg = kbase + (size_t)(w * 16 + srow) * D_MODEL + scolS;
    const u16* vg = vbase + (size_t)(w * 16 + srow) * S_LEN + scolS;

    auto stageKV = [&](int kt, int bsel) {
        ldsload16(kg + (size_t)kt * D_MODEL,      &Ks0[bsel][w * 16][0]);
        ldsload16(kg + (size_t)kt * D_MODEL + 32, &Ks1[bsel][w * 16][0]);
        ldsload16(vg + kt,      &Vs0[bsel][w * 16][0]);
        ldsload16(vg + kt + 32, &Vs1[bsel][w * 16][0]);
    };

    stageKV(0, 0);

    // ---- Q fragments direct from global into regs (once per block) ----
    bf16x8 bq0, bq1;
    {
        const u16* qrow = q + ((size_t)b * S_LEN + st0 + w * 16 + lrow) * D_MODEL + h * DK + quad * 8;
        bq0 = *(const bf16x8*)qrow;
        bq1 = *(const bf16x8*)(qrow + 32);
    }

    // ones vector (bf16 1.0 x8) for MFMA row-sums
    bf16x8 ones;
    {
        union { u16 u; __bf16 b; } o; o.u = 0x3F80;
        #pragma unroll
        for (int j = 0; j < 8; ++j) ones[j] = o.b;
    }

    floatx4 zero = {0.f, 0.f, 0.f, 0.f};
    floatx4 Ot[4] = {zero, zero, zero, zero};
    floatx4 Osum = zero;              // row-sums of P (per-lane rows quad*4+j)

    u64 mw = bw[0];                   // mask bits for tile 0 (prefetched)
    __syncthreads();                  // stageKV(0) landed

    int cur = 0;
    for (int kt = 0; kt < S_LEN; kt += 64) {
        // prefetch next K/V tile -> other LDS buffer, mask word -> reg
        if (kt + 64 < S_LEN) stageKV(kt + 64, cur ^ 1);
        u64 mw_next = (kt + 64 < S_LEN) ? bw[(kt >> 6) + 1] : 0ull;
        unsigned mlo = (unsigned)mw, mhi = (unsigned)(mw >> 32);

        // --- S^T = K Q^T : 64 keys x 16 q per wave ---
        floatx4 st[4];
        #pragma unroll
        for (int nt = 0; nt < 4; ++nt) {
            bf16x8 ak0 = *(const bf16x8*)&Ks0[cur][nt * 16 + lrow][rq];
            bf16x8 ak1 = *(const bf16x8*)&Ks1[cur][nt * 16 + lrow][rq];
            st[nt] = __builtin_amdgcn_mfma_f32_16x16x32_bf16(ak0, bq0, zero, 0, 0, 0);
            st[nt] = __builtin_amdgcn_mfma_f32_16x16x32_bf16(ak1, bq1, st[nt], 0, 0, 0);
        }

        // --- P^T = maskbit * exp2(S^T), truncated to bf16, packed writes ---
        #pragma unroll
        for (int nt = 0; nt < 4; ++nt) {
            unsigned half = (nt & 2) ? mhi : mlo;
            unsigned tmp = half >> ((nt & 1) * 16 + quad * 4);
            unsigned eu[4];
            #pragma unroll
            for (int j = 0; j < 4; ++j) {
                float e = __builtin_amdgcn_exp2f(st[nt][j]);
                unsigned msk = (unsigned)((int)(tmp << (31 - j)) >> 31);
                eu[j] = __float_as_uint(e) & msk;
            }
            uint2 p;
            p.x = (eu[0] >> 16) | (eu[1] & 0xffff0000u);
            p.y = (eu[2] >> 16) | (eu[3] & 0xffff0000u);
            // logical col = nt*16 + quad*4 -> cg = nt*2 + (quad>>1)
            int pc = ((nt * 2 + pch) ^ ptw) * 8 + pqo;
            *(uint2*)&PT[w][lrow][pc] = p;
        }

        // --- O += P V ; row-sums += P * ones (on the MFMA pipe) ---
        bf16x8 ap0 = *(const bf16x8*)&PT[w][lrow][rp0];
        bf16x8 ap1 = *(const bf16x8*)&PT[w][lrow][rp1];
        Osum = __builtin_amdgcn_mfma_f32_16x16x32_bf16(ap0, ones, Osum, 0, 0, 0);
        Osum = __builtin_amdgcn_mfma_f32_16x16x32_bf16(ap1, ones, Osum, 0, 0, 0);
        #pragma unroll
        for (int dt = 0; dt < 4; ++dt) {
            bf16x8 bv0 = *(const bf16x8*)&Vs0[cur][dt * 16 + lrow][rq];
            bf16x8 bv1 = *(const bf16x8*)&Vs1[cur][dt * 16 + lrow][rq];
            Ot[dt] = __builtin_amdgcn_mfma_f32_16x16x32_bf16(ap0, bv0, Ot[dt], 0, 0, 0);
            Ot[dt] = __builtin_amdgcn_mfma_f32_16x16x32_bf16(ap1, bv1, Ot[dt], 0, 0, 0);
        }

        // single barrier per tile: all waves done reading buf[cur] (so next
        // iter may overwrite) and stageKV(kt+64) landed (vmcnt drain).
        __syncthreads();
        cur ^= 1;
        mw = mw_next;
    }

    // --- Osum[j] is the row-sum for q-row quad*4+j (cols identical) ---
    float invj[4];
    #pragma unroll
    for (int j = 0; j < 4; ++j) invj[j] = 1.0f / Osum[j];

    u16* obase = out + ((size_t)b * S_LEN + st0 + w * 16) * D_MODEL + h * DK;
    #pragma unroll
    for (int dt = 0; dt < 4; ++dt)
        #pragma unroll
        for (int j = 0; j < 4; ++j)
            obase[(size_t)(quad * 4 + j) * D_MODEL + dt * 16 + lrow] = f2bf(Ot[dt][j] * invj[j]);
}

// ---------------- host launch ----------------
extern "C" void kernel_launch(void* const* d_in, const int* in_sizes, int n_in,
                              void* d_out, int out_size, void* d_ws, size_t ws_size,
                              hipStream_t stream) {
    const float* x      = (const float*)d_in[0];
    const int*   mask   = (const int*)d_in[1];
    const float* wq     = (const float*)d_in[2];
    const float* wk     = (const float*)d_in[3];
    const float* wv     = (const float*)d_in[4];
    const float* wo     = (const float*)d_in[5];
    const float* w1     = (const float*)d_in[6];
    const float* w2     = (const float*)d_in[7];
    const float* w3     = (const float*)d_in[8];
    const float* g_attn = (const float*)d_in[9];
    const float* g_ffn  = (const float*)d_in[10];
    float* out = (float*)d_out;

    const size_t WSMALL = (size_t)D_MODEL * D_MODEL;
    const size_t WBIG   = (size_t)F_DIM * D_MODEL;
    const size_t MD     = (size_t)M_ROWS * D_MODEL;

    char* ws = (char*)d_ws;
    u16* wqkvf = (u16*)ws;           ws += WSMALL * 3 * 2;  // frag-ordered wq|wk|wv
    u16* wob  = (u16*)ws;            ws += WSMALL * 2;
    u16* w13f = (u16*)ws;            ws += WBIG * 2 * 2;   // frag-ordered w1|w3
    u16* w2b  = (u16*)ws;            ws += WBIG * 2;
    u16* xn  = (u16*)ws;             ws += MD * 2;       // also hn (reuse)
    u16* qb  = (u16*)ws;             ws += MD * 2;       // qb..ao contiguous = ub [M,F]
    u16* kb  = (u16*)ws;             ws += MD * 2;
    u16* vb  = (u16*)ws;             ws += MD * 2;       // V^T [B][NH][DK][S]
    u16* ao  = (u16*)ws;             ws += MD * 2;
    float* hb = (float*)ws;          ws += MD * 4;
    u64* mb  = (u64*)ws;             ws += (size_t)BATCH * S_LEN * (S_LEN / 64) * 8;
    u16* hn = xn;
    u16* ub = qb;   // [M, F] bf16, reuses qb..ao (4*MD == M*F)
    (void)ws_size; (void)n_in; (void)in_sizes; (void)out_size;

    dim3 blk(256);

    prep<<<17408, blk, 0, stream>>>((const float4*)wq, (const float4*)wk, (const float4*)wv,
                                    (const float4*)wo, (const float4*)w1, (const float4*)w2,
                                    (const float4*)w3,
                                    (ushort4*)wqkvf, (ushort4*)wob, (ushort4*)w13f, (ushort4*)w2b,
                                    mask, mb, x, g_attn, xn);

    gemm_qkv<<<dim3(18, M_ROWS / 64), blk, 0, stream>>>(xn, wqkvf, qb, kb, vb);
    attn_mfma<<<dim3(S_LEN / 64, BATCH * NH), blk, 0, stream>>>(qb, kb, vb, mb, ao);
    gemm64<<<dim3(D_MODEL / 64, M_ROWS / 64), blk, 0, stream>>>(ao, wob, x, hb, D_MODEL, D_MODEL);
    rmsnorm_k<<<M_ROWS, blk, 0, stream>>>((const float*)hb, g_ffn, hn);
    gemm_f1<<<dim3(24, M_ROWS / 64), blk, 0, stream>>>(hn, w13f, ub);
    gemm64<<<dim3(D_MODEL / 64, M_ROWS / 64), blk, 0, stream>>>(ub, w2b, hb, out, D_MODEL, F_DIM);
}